// Round 3
// baseline (284.320 us; speedup 1.0000x reference)
//
#include <hip/hip_runtime.h>
#include <math.h>

#define NN 8192
#define DD 256
#define EPSV 1e-6f
#define BM 64
#define BN 64
#define CSPLIT 4
#define COLS_PER_BLOCK (NN / CSPLIT)  // 2048
#define NJT (COLS_PER_BLOCK / BN)     // 32
#define PSTR 72                       // P LDS row stride (bf16), 16B aligned, bank-rotating
#define TSTR 266                      // prep transpose LDS stride (ushorts), %4==2 -> 2-way max

typedef __bf16 bf16x8 __attribute__((ext_vector_type(8)));
typedef float f32x16 __attribute__((ext_vector_type(16)));
typedef unsigned short ushort;
typedef unsigned int uint;

// ws layout (floats): Oacc[NN*DD] | lacc[NN] | qn[NN] | itv2[NN] | qbf[NN*DD/2] | qbfT[NN*DD/2]

__device__ inline ushort f2bf(float x) {
    uint u = __float_as_uint(x);
    u += 0x7fffu + ((u >> 16) & 1u);
    return (ushort)(u >> 16);
}

__device__ inline void gload_lds16(const void* g, void* l) {
    __builtin_amdgcn_global_load_lds((const __attribute__((address_space(1))) uint*)g,
                                     (__attribute__((address_space(3))) uint*)l, 16, 0, 0);
}

__global__ void zero_kernel(float* __restrict__ p) {
    int i = blockIdx.x * 256 + threadIdx.x;
    ((float4*)p)[i] = make_float4(0.f, 0.f, 0.f, 0.f);
}

// Fused: q -> qbf (swizzled), qbfT (unswizzled [DD][NN]), qn, itv2 = sqrt(2c)/t
__global__ void prep_kernel(const float* __restrict__ q, const float* __restrict__ cp,
                            ushort* __restrict__ qbf, ushort* __restrict__ qbfT,
                            float* __restrict__ qn, float* __restrict__ itv2) {
    __shared__ ushort T[64 * TSTR];
    const int t = threadIdx.x;
    const int p0 = blockIdx.x * 64;
    const int pr = t >> 2, fq = t & 3;
    const int row = p0 + pr;
    const float4* src = (const float4*)(q + (size_t)row * DD + fq * 64);
    ushort loc[64];
    float ss = 0.f;
    #pragma unroll
    for (int i = 0; i < 16; ++i) {
        float4 v = src[i];
        ushort b0 = f2bf(v.x), b1 = f2bf(v.y), b2 = f2bf(v.z), b3 = f2bf(v.w);
        loc[i * 4 + 0] = b0; loc[i * 4 + 1] = b1; loc[i * 4 + 2] = b2; loc[i * 4 + 3] = b3;
        float r0 = __uint_as_float((uint)b0 << 16), r1 = __uint_as_float((uint)b1 << 16);
        float r2 = __uint_as_float((uint)b2 << 16), r3 = __uint_as_float((uint)b3 << 16);
        ss += r0 * r0 + r1 * r1 + r2 * r2 + r3 * r3;
    }
    // qbf swizzled write: chunk c = fq*8+k stored at (c ^ (row&7))
    #pragma unroll
    for (int k = 0; k < 8; ++k)
        *(uint4*)(qbf + (size_t)row * DD + (((fq * 8 + k) ^ (row & 7)) * 8)) = *(uint4*)&loc[k * 8];
    // stage into LDS for transpose (ushort2 stores: 4B aligned for odd strides)
    #pragma unroll
    for (int k = 0; k < 32; ++k)
        *(ushort2*)&T[pr * TSTR + fq * 64 + k * 2] = *(ushort2*)&loc[k * 2];
    // qn / itv2
    ss += __shfl_xor(ss, 1, 64);
    ss += __shfl_xor(ss, 2, 64);
    if (fq == 0) {
        float cc = fmaxf(cp[0], EPSV);
        qn[row] = ss;
        float tt = fmaxf(1.0f - cc * ss, EPSV);
        itv2[row] = sqrtf(2.0f * cc) / tt;
    }
    __syncthreads();
    // transposed write: qbfT[f][p0..p0+63]
    #pragma unroll
    for (int pass = 0; pass < 4; ++pass) {
        int f = pass * 64 + (t >> 2);
        int quarter = t & 3;
        ushort tmp[16];
        #pragma unroll
        for (int i = 0; i < 16; ++i) tmp[i] = T[(quarter * 16 + i) * TSTR + f];
        *(uint4*)(qbfT + (size_t)f * NN + p0 + quarter * 16) = *(uint4*)&tmp[0];
        *(uint4*)(qbfT + (size_t)f * NN + p0 + quarter * 16 + 8) = *(uint4*)&tmp[8];
    }
}

__global__ __launch_bounds__(256, 2) void flash_kernel(
    const ushort* __restrict__ qbf, const ushort* __restrict__ qbfT,
    const float* __restrict__ cp, const float* __restrict__ qn,
    const float* __restrict__ itv2, float* __restrict__ Oacc, float* __restrict__ lacc) {
    __shared__ ushort Klds[64 * 256];   // 32 KB, swizzled rows
    __shared__ ushort Plds[64 * PSTR];  // 9 KB

    const int tid = threadIdx.x;
    const int lane = tid & 63;
    const int w = tid >> 6;
    const int l31 = lane & 31;
    const int lhi = lane >> 5;
    const int qr = w >> 1;
    const int qc = w & 1;
    const int R0 = blockIdx.y * BM;
    const int C0 = blockIdx.x * COLS_PER_BLOCK;

    const float cc = fmaxf(cp[0], EPSV);
    const float rsc = rsqrtf(cc);

    // persistent Q A-fragments (32 rows x 256 K)
    const int rowA = R0 + qr * 32 + l31;
    const ushort* qrow = qbf + (size_t)rowA * DD;
    bf16x8 qa[16];
    #pragma unroll
    for (int kk = 0; kk < 16; ++kk) {
        int c = kk * 2 + lhi;
        qa[kk] = *(const bf16x8*)(qrow + ((c ^ (rowA & 7)) * 8));
    }

    float qnr16[16], itr16[16];
    #pragma unroll
    for (int r = 0; r < 16; ++r) {
        int row = R0 + qr * 32 + (r & 3) + 8 * (r >> 2) + 4 * lhi;
        qnr16[r] = qn[row];
        itr16[r] = itv2[row];
    }

    f32x16 o[4];
    #pragma unroll
    for (int ct = 0; ct < 4; ++ct)
        #pragma unroll
        for (int i = 0; i < 16; ++i) o[ct][i] = 0.f;
    float racc[16];
    #pragma unroll
    for (int r = 0; r < 16; ++r) racc[r] = 0.f;

    // V-frag global base pointers: lane covers feature d = qc*128 + ct*32 + l31
    const ushort* vbase[4];
    #pragma unroll
    for (int ct = 0; ct < 4; ++ct)
        vbase[ct] = qbfT + (size_t)(qc * 128 + ct * 32 + l31) * NN + 8 * lhi;

    // stage K(0)
    {
        const char* gbase = (const char*)(qbf + (size_t)C0 * DD);
        #pragma unroll
        for (int i = 0; i < 8; ++i) {
            int chunk = w * 8 + i;
            gload_lds16(gbase + chunk * 1024 + lane * 16, (char*)Klds + chunk * 1024);
        }
    }

    for (int jt = 0; jt < NJT; ++jt) {
        const int C = C0 + jt * BN;
        __syncthreads();  // A: K(jt) arrived; prev PV done with Plds

        // ---- S = Q . K^T ----
        f32x16 s;
        #pragma unroll
        for (int i = 0; i < 16; ++i) s[i] = 0.f;
        const int jrow = qc * 32 + l31;
        const ushort* krow = Klds + jrow * DD;
        #pragma unroll
        for (int kk = 0; kk < 16; ++kk) {
            int c = kk * 2 + lhi;
            bf16x8 b = *(const bf16x8*)(krow + ((c ^ (jrow & 7)) * 8));
            s = __builtin_amdgcn_mfma_f32_32x32x16_bf16(qa[kk], b, s, 0, 0, 0);
        }

        // ---- elementwise hyperbolic -> P ----
        {
            int J = C + jrow;
            float qnj = qn[J];
            float itj = itv2[J];
            #pragma unroll
            for (int r = 0; r < 16; ++r) {
                int mloc = qr * 32 + (r & 3) + 8 * (r >> 2) + 4 * lhi;
                float diff = fmaxf(qnr16[r] + qnj - 2.0f * s[r], 0.0f);
                float u = diff * itr16[r] * itj;
                float z = fmaxf(1.0f + u, 1.0f + EPSV) + EPSV;
                float y = z + sqrtf(fmaf(z, z, -1.0f));
                float p = __builtin_amdgcn_exp2f(-rsc * __builtin_amdgcn_logf(y));
                racc[r] += p;
                Plds[mloc * PSTR + jrow] = f2bf(p);
            }
        }

        // V-frags for kt=0 can fly during the barrier drain
        bf16x8 vb0[4];
        #pragma unroll
        for (int ct = 0; ct < 4; ++ct) vb0[ct] = *(const bf16x8*)(vbase[ct] + C);

        __syncthreads();  // B: P ready; all S reads of Klds done

        // ---- overlap: stage K(jt+1) ----
        if (jt + 1 < NJT) {
            const char* gbase = (const char*)(qbf + (size_t)(C + BN) * DD);
            #pragma unroll
            for (int i = 0; i < 8; ++i) {
                int chunk = w * 8 + i;
                gload_lds16(gbase + chunk * 1024 + lane * 16, (char*)Klds + chunk * 1024);
            }
        }

        // ---- O += P . V (B-frags direct from global qbfT) ----
        bf16x8 cur[4], nxt[4];
        #pragma unroll
        for (int ct = 0; ct < 4; ++ct) cur[ct] = vb0[ct];
        #pragma unroll
        for (int kt = 0; kt < 4; ++kt) {
            if (kt < 3) {
                #pragma unroll
                for (int ct = 0; ct < 4; ++ct)
                    nxt[ct] = *(const bf16x8*)(vbase[ct] + C + (kt + 1) * 16);
            }
            bf16x8 pa = *(const bf16x8*)&Plds[(qr * 32 + l31) * PSTR + kt * 16 + 8 * lhi];
            #pragma unroll
            for (int ct = 0; ct < 4; ++ct)
                o[ct] = __builtin_amdgcn_mfma_f32_32x32x16_bf16(pa, cur[ct], o[ct], 0, 0, 0);
            #pragma unroll
            for (int ct = 0; ct < 4; ++ct) cur[ct] = nxt[ct];
        }
    }

    // ---- epilogue ----
    #pragma unroll
    for (int ct = 0; ct < 4; ++ct) {
        #pragma unroll
        for (int r = 0; r < 16; ++r) {
            int row = R0 + qr * 32 + (r & 3) + 8 * (r >> 2) + 4 * lhi;
            int d = qc * 128 + ct * 32 + l31;
            atomicAdd(&Oacc[(size_t)row * DD + d], o[ct][r]);
        }
    }
    // reduce racc across the 32 l31-lanes (lhi fixed per half)
    #pragma unroll
    for (int off = 1; off <= 16; off <<= 1)
        #pragma unroll
        for (int r = 0; r < 16; ++r) racc[r] += __shfl_xor(racc[r], off, 64);
    if (l31 == 0) {
        #pragma unroll
        for (int r = 0; r < 16; ++r) {
            int row = R0 + qr * 32 + (r & 3) + 8 * (r >> 2) + 4 * lhi;
            atomicAdd(&lacc[row], racc[r]);
        }
    }
}

__global__ void norm_kernel(const float* __restrict__ Oacc, const float* __restrict__ lacc,
                            float* __restrict__ out) {
    int i = blockIdx.x * 256 + threadIdx.x;
    float4 v = ((const float4*)Oacc)[i];
    float inv = 1.0f / lacc[i >> 6];
    ((float4*)out)[i] = make_float4(v.x * inv, v.y * inv, v.z * inv, v.w * inv);
}

extern "C" void kernel_launch(void* const* d_in, const int* in_sizes, int n_in,
                              void* d_out, int out_size, void* d_ws, size_t ws_size,
                              hipStream_t stream) {
    (void)in_sizes; (void)n_in; (void)out_size; (void)ws_size;
    const float* q = (const float*)d_in[0];
    const float* cp = (const float*)d_in[1];
    float* out = (float*)d_out;
    float* ws = (float*)d_ws;
    float* Oacc = ws;
    float* lacc = ws + (size_t)NN * DD;
    float* qn = lacc + NN;
    float* itv2 = qn + NN;
    ushort* qbf = (ushort*)(itv2 + NN);
    ushort* qbfT = qbf + (size_t)NN * DD;

    zero_kernel<<<(NN * DD + NN) / 4 / 256, 256, 0, stream>>>(ws);
    prep_kernel<<<NN / 64, 256, 0, stream>>>(q, cp, qbf, qbfT, qn, itv2);
    flash_kernel<<<dim3(CSPLIT, NN / BM), 256, 0, stream>>>(qbf, qbfT, cp, qn, itv2, Oacc, lacc);
    norm_kernel<<<(NN * DD / 4) / 256, 256, 0, stream>>>(Oacc, lacc, out);
}

// Round 5
// 205.633 us; speedup vs baseline: 1.3827x; 1.3827x over previous
//
#include <hip/hip_runtime.h>
#include <math.h>

#define NN 8192
#define DD 256
#define EPSV 1e-6f
#define BM 128
#define BN 64
#define CSPLIT 4
#define COLS_PER_BLOCK (NN / CSPLIT)  // 2048
#define NJT (COLS_PER_BLOCK / BN)     // 32
#define PSTR 72                       // P LDS row stride (bf16), 16B aligned
#define TSTR 266                      // prep transpose LDS stride
// dynamic LDS: Kbuf0 32KB | Kbuf1 32KB | Ktlds 32KB | Plds 128*72*2 = 18432
#define SMEM_BYTES (32768 * 3 + BM * PSTR * 2)  // 116736

typedef __bf16 bf16x8 __attribute__((ext_vector_type(8)));
typedef float f32x16 __attribute__((ext_vector_type(16)));
typedef unsigned short ushort;
typedef unsigned int uint;

// ws layout (floats): Oacc[NN*DD] | lacc[NN] | qn[NN] | itv2[NN] | qbf[NN*DD/2] | qbfT[NN*DD/2]

__device__ inline ushort f2bf(float x) {
    uint u = __float_as_uint(x);
    u += 0x7fffu + ((u >> 16) & 1u);
    return (ushort)(u >> 16);
}

__device__ inline void gload_lds16(const void* g, void* l) {
    __builtin_amdgcn_global_load_lds((const __attribute__((address_space(1))) uint*)g,
                                     (__attribute__((address_space(3))) uint*)l, 16, 0, 0);
}

__global__ void zero_kernel(float* __restrict__ p) {
    int i = blockIdx.x * 256 + threadIdx.x;
    ((float4*)p)[i] = make_float4(0.f, 0.f, 0.f, 0.f);
}

// Fused: q -> qbf (16B-chunk swizzled rows), qbfT ([DD][NN]), qn (from bf16 q), itv2 = sqrt(2c)/t
__global__ void prep_kernel(const float* __restrict__ q, const float* __restrict__ cp,
                            ushort* __restrict__ qbf, ushort* __restrict__ qbfT,
                            float* __restrict__ qn, float* __restrict__ itv2) {
    __shared__ ushort T[64 * TSTR];
    const int t = threadIdx.x;
    const int p0 = blockIdx.x * 64;
    const int pr = t >> 2, fq = t & 3;
    const int row = p0 + pr;
    const float4* src = (const float4*)(q + (size_t)row * DD + fq * 64);
    ushort loc[64];
    float ss = 0.f;
    #pragma unroll
    for (int i = 0; i < 16; ++i) {
        float4 v = src[i];
        ushort b0 = f2bf(v.x), b1 = f2bf(v.y), b2 = f2bf(v.z), b3 = f2bf(v.w);
        loc[i * 4 + 0] = b0; loc[i * 4 + 1] = b1; loc[i * 4 + 2] = b2; loc[i * 4 + 3] = b3;
        float r0 = __uint_as_float((uint)b0 << 16), r1 = __uint_as_float((uint)b1 << 16);
        float r2 = __uint_as_float((uint)b2 << 16), r3 = __uint_as_float((uint)b3 << 16);
        ss += r0 * r0 + r1 * r1 + r2 * r2 + r3 * r3;
    }
    #pragma unroll
    for (int k = 0; k < 8; ++k)
        *(uint4*)(qbf + (size_t)row * DD + (((fq * 8 + k) ^ (row & 7)) * 8)) = *(uint4*)&loc[k * 8];
    #pragma unroll
    for (int k = 0; k < 32; ++k)
        *(ushort2*)&T[pr * TSTR + fq * 64 + k * 2] = *(ushort2*)&loc[k * 2];
    ss += __shfl_xor(ss, 1, 64);
    ss += __shfl_xor(ss, 2, 64);
    if (fq == 0) {
        float cc = fmaxf(cp[0], EPSV);
        qn[row] = ss;
        float tt = fmaxf(1.0f - cc * ss, EPSV);
        itv2[row] = sqrtf(2.0f * cc) / tt;
    }
    __syncthreads();
    #pragma unroll
    for (int pass = 0; pass < 4; ++pass) {
        int f = pass * 64 + (t >> 2);
        int quarter = t & 3;
        ushort tmp[16];
        #pragma unroll
        for (int i = 0; i < 16; ++i) tmp[i] = T[(quarter * 16 + i) * TSTR + f];
        *(uint4*)(qbfT + (size_t)f * NN + p0 + quarter * 16) = *(uint4*)&tmp[0];
        *(uint4*)(qbfT + (size_t)f * NN + p0 + quarter * 16 + 8) = *(uint4*)&tmp[8];
    }
}

__global__ __launch_bounds__(512, 2) void flash_kernel(
    const ushort* __restrict__ qbf, const ushort* __restrict__ qbfT,
    const float* __restrict__ cp, const float* __restrict__ qn,
    const float* __restrict__ itv2, float* __restrict__ Oacc, float* __restrict__ lacc) {
    extern __shared__ char smem[];
    ushort* Ktlds = (ushort*)(smem + 65536);   // [256 f][64 j], chunk-swizzled per row
    ushort* Plds = (ushort*)(smem + 98304);    // [128][PSTR]

    const int tid = threadIdx.x;
    const int lane = tid & 63;
    const int w = tid >> 6;     // 0..7
    const int l31 = lane & 31;
    const int lhi = lane >> 5;
    const int qr = w >> 1;      // 0..3: S rows 32*qr
    const int qc = w & 1;       // S cols 32*qc; O feats 128*qc
    const int R0 = blockIdx.y * BM;
    const int C0 = blockIdx.x * COLS_PER_BLOCK;

    const float cc = fmaxf(cp[0], EPSV);
    const float rsc = rsqrtf(cc);

    // persistent Q A-fragments (rows R0 + qr*32 + l31, all 256 K)
    const int rowA = R0 + qr * 32 + l31;
    const ushort* qrow = qbf + (size_t)rowA * DD;
    bf16x8 qa[16];
    #pragma unroll
    for (int kk = 0; kk < 16; ++kk) {
        int c = kk * 2 + lhi;
        qa[kk] = *(const bf16x8*)(qrow + ((c ^ (rowA & 7)) * 8));
    }

    float qnr16[16], itr16[16];
    #pragma unroll
    for (int r = 0; r < 16; ++r) {
        int row = R0 + qr * 32 + (r & 3) + 8 * (r >> 2) + 4 * lhi;
        qnr16[r] = qn[row];
        itr16[r] = itv2[row];
    }

    f32x16 o[4];
    #pragma unroll
    for (int ct = 0; ct < 4; ++ct)
        #pragma unroll
        for (int i = 0; i < 16; ++i) o[ct][i] = 0.f;
    float racc[16];
    #pragma unroll
    for (int r = 0; r < 16; ++r) racc[r] = 0.f;

    // ---- stage K(0) into buf 0: 32 KB contiguous from qbf rows C0.. ----
    {
        const char* g = (const char*)(qbf + (size_t)C0 * DD);
        #pragma unroll
        for (int i = 0; i < 4; ++i) {
            int base = i * 8192 + w * 1024;
            gload_lds16(g + base + lane * 16, smem + base);
        }
    }

    #pragma unroll 1
    for (int jt = 0; jt < NJT; ++jt) {
        const int C = C0 + jt * BN;
        const ushort* Kc = (const ushort*)(smem + (jt & 1) * 32768);
        __syncthreads();  // A: K(jt) ready; Ktlds/Plds/other Kbuf free

        // ---- issue staging: K(jt+1) -> other buf; Kt(jt) -> Ktlds ----
        if (jt + 1 < NJT) {
            const char* g = (const char*)(qbf + (size_t)(C + BN) * DD);
            char* dst = smem + ((jt + 1) & 1) * 32768;
            #pragma unroll
            for (int i = 0; i < 4; ++i) {
                int base = i * 8192 + w * 1024;
                gload_lds16(g + base + lane * 16, dst + base);
            }
        }
        {
            // Kt: rows f (features), 64 j-cols; global-side swizzle so stored
            // chunk p of row f holds logical chunk p ^ (f&7)
            #pragma unroll
            for (int i = 0; i < 4; ++i) {
                int f0 = i * 64 + w * 8;
                int f = f0 + (lane >> 3);
                const char* g = (const char*)(qbfT + (size_t)f * NN + C) +
                                (((lane & 7) ^ (f & 7)) * 16);
                gload_lds16(g, (char*)Ktlds + f0 * 128);
            }
        }

        // ---- S = Q . K^T (wave: rows 32*qr, cols 32*qc) ----
        f32x16 s;
        #pragma unroll
        for (int i = 0; i < 16; ++i) s[i] = 0.f;
        const int jrow = qc * 32 + l31;
        const ushort* krow = Kc + jrow * DD;
        #pragma unroll
        for (int kk = 0; kk < 16; ++kk) {
            int c = kk * 2 + lhi;
            bf16x8 b = *(const bf16x8*)(krow + ((c ^ (jrow & 7)) * 8));
            s = __builtin_amdgcn_mfma_f32_32x32x16_bf16(qa[kk], b, s, 0, 0, 0);
        }

        // ---- elementwise hyperbolic -> P (bf16, LDS), racc in regs ----
        {
            int J = C + jrow;
            float qnj = qn[J];
            float itj = itv2[J];
            #pragma unroll
            for (int r = 0; r < 16; ++r) {
                int mloc = qr * 32 + (r & 3) + 8 * (r >> 2) + 4 * lhi;
                float diff = fmaxf(qnr16[r] + qnj - 2.0f * s[r], 0.0f);
                float u = diff * itr16[r] * itj;
                float z = fmaxf(1.0f + u, 1.0f + EPSV) + EPSV;
                float y = z + sqrtf(fmaf(z, z, -1.0f));
                float p = __builtin_amdgcn_exp2f(-rsc * __builtin_amdgcn_logf(y));
                racc[r] += p;
                Plds[mloc * PSTR + jrow] = f2bf(p);
            }
        }
        __syncthreads();  // B: P visible; Kt(jt) drained; S reads of Kc done

        // ---- O += P . V (A from Plds, B from Ktlds) ----
        #pragma unroll
        for (int kt = 0; kt < 4; ++kt) {
            bf16x8 pa = *(const bf16x8*)&Plds[(qr * 32 + l31) * PSTR + kt * 16 + 8 * lhi];
            #pragma unroll
            for (int ct = 0; ct < 4; ++ct) {
                int f = qc * 128 + ct * 32 + l31;
                int cj = kt * 2 + lhi;
                bf16x8 vb = *(const bf16x8*)(Ktlds + f * 64 + (((cj ^ (f & 7))) * 8));
                o[ct] = __builtin_amdgcn_mfma_f32_32x32x16_bf16(pa, vb, o[ct], 0, 0, 0);
            }
        }
    }

    // ---- epilogue ----
    #pragma unroll
    for (int ct = 0; ct < 4; ++ct) {
        #pragma unroll
        for (int r = 0; r < 16; ++r) {
            int row = R0 + qr * 32 + (r & 3) + 8 * (r >> 2) + 4 * lhi;
            int d = qc * 128 + ct * 32 + l31;
            atomicAdd(&Oacc[(size_t)row * DD + d], o[ct][r]);
        }
    }
    #pragma unroll
    for (int off = 1; off <= 16; off <<= 1)
        #pragma unroll
        for (int r = 0; r < 16; ++r) racc[r] += __shfl_xor(racc[r], off, 64);
    if (l31 == 0) {
        #pragma unroll
        for (int r = 0; r < 16; ++r) {
            int row = R0 + qr * 32 + (r & 3) + 8 * (r >> 2) + 4 * lhi;
            atomicAdd(&lacc[row], racc[r]);
        }
    }
}

__global__ void norm_kernel(const float* __restrict__ Oacc, const float* __restrict__ lacc,
                            float* __restrict__ out) {
    int i = blockIdx.x * 256 + threadIdx.x;
    float4 v = ((const float4*)Oacc)[i];
    float inv = 1.0f / lacc[i >> 6];
    ((float4*)out)[i] = make_float4(v.x * inv, v.y * inv, v.z * inv, v.w * inv);
}

extern "C" void kernel_launch(void* const* d_in, const int* in_sizes, int n_in,
                              void* d_out, int out_size, void* d_ws, size_t ws_size,
                              hipStream_t stream) {
    (void)in_sizes; (void)n_in; (void)out_size; (void)ws_size;
    const float* q = (const float*)d_in[0];
    const float* cp = (const float*)d_in[1];
    float* out = (float*)d_out;
    float* ws = (float*)d_ws;
    float* Oacc = ws;
    float* lacc = ws + (size_t)NN * DD;
    float* qn = lacc + NN;
    float* itv2 = qn + NN;
    ushort* qbf = (ushort*)(itv2 + NN);
    ushort* qbfT = qbf + (size_t)NN * DD;

    (void)hipFuncSetAttribute((const void*)flash_kernel,
                              hipFuncAttributeMaxDynamicSharedMemorySize, SMEM_BYTES);

    zero_kernel<<<(NN * DD + NN) / 4 / 256, 256, 0, stream>>>(ws);
    prep_kernel<<<NN / 64, 256, 0, stream>>>(q, cp, qbf, qbfT, qn, itv2);
    flash_kernel<<<dim3(CSPLIT, NN / BM), 512, SMEM_BYTES, stream>>>(qbf, qbfT, cp, qn, itv2, Oacc, lacc);
    norm_kernel<<<(NN * DD / 4) / 256, 256, 0, stream>>>(Oacc, lacc, out);
}